// Round 1
// baseline (15087.482 us; speedup 1.0000x reference)
//
#include <hip/hip_runtime.h>
#include <hip/hip_bf16.h>

namespace {
constexpr int kNC = 50000;
constexpr int kNT = 30000;
constexpr int kND = 20000;
constexpr int kN  = 100000;   // total nodes
constexpr int kR  = 4;        // relations
constexpr int kER = 400000;   // edges per relation
constexpr int kH  = 256;      // hidden dim
}

#define TILE_M 64
#define TILE_N 64
#define TILE_K 16

// C[M, 256] (+)= A[M, K] @ B[K, 256]  (+ bias when not accumulating)
__global__ __launch_bounds__(256)
void gemm_f32(const float* __restrict__ A, const float* __restrict__ B,
              const float* __restrict__ bias, float* __restrict__ C,
              int M, int K, int accumulate)
{
    __shared__ float As[TILE_K][TILE_M + 1];
    __shared__ float Bs[TILE_K][TILE_N + 1];
    const int tid = threadIdx.x;
    const int tx = tid & 15;   // N direction (4 cols each)
    const int ty = tid >> 4;   // M direction (4 rows each)
    const int row0 = blockIdx.y * TILE_M;
    const int col0 = blockIdx.x * TILE_N;

    float acc[4][4] = {};

    for (int k0 = 0; k0 < K; k0 += TILE_K) {
        // Load A tile (64 x 16), store transposed As[k][m]
        for (int i = tid; i < TILE_M * TILE_K; i += 256) {
            int r = i >> 4;    // 0..63 (m)
            int c = i & 15;    // 0..15 (k)
            int gr = row0 + r;
            As[c][r] = (gr < M) ? A[(size_t)gr * K + (k0 + c)] : 0.0f;
        }
        // Load B tile (16 x 64)
        for (int i = tid; i < TILE_K * TILE_N; i += 256) {
            int r = i >> 6;    // 0..15 (k)
            int c = i & 63;    // 0..63 (n)
            Bs[r][c] = B[(size_t)(k0 + r) * kH + (col0 + c)];
        }
        __syncthreads();
        #pragma unroll
        for (int kk = 0; kk < TILE_K; ++kk) {
            float a[4], b[4];
            #pragma unroll
            for (int i = 0; i < 4; ++i) a[i] = As[kk][ty * 4 + i];
            #pragma unroll
            for (int j = 0; j < 4; ++j) b[j] = Bs[kk][tx * 4 + j];
            #pragma unroll
            for (int i = 0; i < 4; ++i)
                #pragma unroll
                for (int j = 0; j < 4; ++j)
                    acc[i][j] += a[i] * b[j];
        }
        __syncthreads();
    }

    #pragma unroll
    for (int i = 0; i < 4; ++i) {
        int gr = row0 + ty * 4 + i;
        if (gr >= M) continue;
        #pragma unroll
        for (int j = 0; j < 4; ++j) {
            int gc = col0 + tx * 4 + j;
            size_t idx = (size_t)gr * kH + gc;
            if (accumulate) C[idx] += acc[i][j];
            else            C[idx] = acc[i][j] + (bias ? bias[gc] : 0.0f);
        }
    }
}

// For each edge e: agg[dst[e], :] += h[src[e], :]   (one wave per edge)
__global__ __launch_bounds__(256)
void scatter_add(const float* __restrict__ h, const int* __restrict__ src,
                 const int* __restrict__ dst, float* __restrict__ agg, int nE)
{
    const int lane = threadIdx.x & 63;
    const int wid  = (blockIdx.x * blockDim.x + threadIdx.x) >> 6;
    const int nw   = (gridDim.x * blockDim.x) >> 6;
    for (int e = wid; e < nE; e += nw) {
        const int s = src[e];
        const int d = dst[e];
        const float4 v = *reinterpret_cast<const float4*>(h + (size_t)s * kH + lane * 4);
        float* dp = agg + (size_t)d * kH + lane * 4;
        atomicAdd(dp + 0, v.x);
        atomicAdd(dp + 1, v.y);
        atomicAdd(dp + 2, v.z);
        atomicAdd(dp + 3, v.w);
    }
}

// out_row = LN(xin_row [+ res_row]) * g + b    (one wave per row)
__global__ __launch_bounds__(256)
void ln_resid(const float* __restrict__ xin, const float* __restrict__ res,
              const float* __restrict__ g, const float* __restrict__ b,
              float* __restrict__ out, int nRows)
{
    const int lane = threadIdx.x & 63;
    const int row  = (int)((blockIdx.x * (size_t)blockDim.x + threadIdx.x) >> 6);
    if (row >= nRows) return;
    float4 v = *reinterpret_cast<const float4*>(xin + (size_t)row * kH + lane * 4);
    if (res) {
        float4 rr = *reinterpret_cast<const float4*>(res + (size_t)row * kH + lane * 4);
        v.x += rr.x; v.y += rr.y; v.z += rr.z; v.w += rr.w;
    }
    float s = v.x + v.y + v.z + v.w;
    #pragma unroll
    for (int o = 32; o >= 1; o >>= 1) s += __shfl_xor(s, o);
    const float mu = s * (1.0f / kH);
    const float dx = v.x - mu, dy = v.y - mu, dz = v.z - mu, dw = v.w - mu;
    float q = dx * dx + dy * dy + dz * dz + dw * dw;
    #pragma unroll
    for (int o = 32; o >= 1; o >>= 1) q += __shfl_xor(q, o);
    const float rstd = rsqrtf(q * (1.0f / kH) + 1e-5f);
    const float4 gg = *reinterpret_cast<const float4*>(g + lane * 4);
    const float4 bb = *reinterpret_cast<const float4*>(b + lane * 4);
    float4 o4;
    o4.x = dx * rstd * gg.x + bb.x;
    o4.y = dy * rstd * gg.y + bb.y;
    o4.z = dz * rstd * gg.z + bb.z;
    o4.w = dw * rstd * gg.w + bb.w;
    *reinterpret_cast<float4*>(out + (size_t)row * kH + lane * 4) = o4;
}

extern "C" void kernel_launch(void* const* d_in, const int* in_sizes, int n_in,
                              void* d_out, int out_size, void* d_ws, size_t ws_size,
                              hipStream_t stream)
{
    const float* x_c  = (const float*)d_in[0];
    const float* x_t  = (const float*)d_in[1];
    const float* x_d  = (const float*)d_in[2];
    const int*   ei   = (const int*)d_in[3];      // [2, R*E_R]
    const float* Wp_c = (const float*)d_in[4];
    const float* bp_c = (const float*)d_in[5];
    const float* Wp_t = (const float*)d_in[6];
    const float* bp_t = (const float*)d_in[7];
    const float* Wp_d = (const float*)d_in[8];
    const float* bp_d = (const float*)d_in[9];
    const float* rgcn_w    = (const float*)d_in[10]; // [2,4,256,256]
    const float* rgcn_root = (const float*)d_in[11]; // [2,256,256]
    const float* rgcn_b    = (const float*)d_in[12]; // [2,256]
    const float* ln_g = (const float*)d_in[13];      // [2,256]
    const float* ln_b = (const float*)d_in[14];      // [2,256]
    const float* Wo   = (const float*)d_in[15];      // [256,256]
    const float* bo   = (const float*)d_in[16];      // [256]

    float* h   = (float*)d_ws;                       // [N, 256]
    float* agg = h + (size_t)kN * kH;                // [N, 256]
    float* out = (float*)d_out;                      // [N, 256] (reused as layer scratch)

    const dim3 blk(256);

    // ---- projections: h = concat(x_c@Wp_c+b, x_t@Wp_t+b, x_d@Wp_d+b)
    {
        dim3 g1(kH / TILE_N, (kNC + TILE_M - 1) / TILE_M);
        gemm_f32<<<g1, blk, 0, stream>>>(x_c, Wp_c, bp_c, h, kNC, 256, 0);
        dim3 g2(kH / TILE_N, (kNT + TILE_M - 1) / TILE_M);
        gemm_f32<<<g2, blk, 0, stream>>>(x_t, Wp_t, bp_t, h + (size_t)kNC * kH, kNT, 512, 0);
        dim3 g3(kH / TILE_N, (kND + TILE_M - 1) / TILE_M);
        gemm_f32<<<g3, blk, 0, stream>>>(x_d, Wp_d, bp_d, h + (size_t)(kNC + kNT) * kH, kND, 128, 0);
    }

    const int* src_base = ei;                        // row 0
    const int* dst_base = ei + (size_t)kR * kER;     // row 1

    const dim3 gemmN(kH / TILE_N, (kN + TILE_M - 1) / TILE_M);

    for (int l = 0; l < 2; ++l) {
        // out = h @ root[l] + b[l]
        gemm_f32<<<gemmN, blk, 0, stream>>>(h, rgcn_root + (size_t)l * kH * kH,
                                            rgcn_b + (size_t)l * kH, out, kN, kH, 0);
        for (int r = 0; r < kR; ++r) {
            // agg = segment_sum(h[src], dst); out += agg @ w[l][r]
            hipMemsetAsync(agg, 0, (size_t)kN * kH * sizeof(float), stream);
            scatter_add<<<dim3((kER + 3) / 4), blk, 0, stream>>>(
                h, src_base + (size_t)r * kER, dst_base + (size_t)r * kER, agg, kER);
            gemm_f32<<<gemmN, blk, 0, stream>>>(
                agg, rgcn_w + (size_t)(l * kR + r) * kH * kH, nullptr, out, kN, kH, 1);
        }
        // h = LN(out [+ h]) * g[l] + b[l]
        ln_resid<<<dim3((kN + 3) / 4), blk, 0, stream>>>(
            out, (l > 0) ? h : nullptr, ln_g + (size_t)l * kH, ln_b + (size_t)l * kH, h, kN);
    }

    // y = h @ Wo + bo  -> d_out
    gemm_f32<<<gemmN, blk, 0, stream>>>(h, Wo, bo, out, kN, kH, 0);
}

// Round 2
// 4987.414 us; speedup vs baseline: 3.0251x; 3.0251x over previous
//
#include <hip/hip_runtime.h>
#include <hip/hip_bf16.h>

namespace {
constexpr int kNC = 50000;
constexpr int kNT = 30000;
constexpr int kND = 20000;
constexpr int kN  = 100000;   // total nodes
constexpr int kR  = 4;        // relations
constexpr int kER = 400000;   // edges per relation
constexpr int kE  = kR * kER; // 1.6M edges
constexpr int kH  = 256;      // hidden dim
constexpr int kB  = kR * kN;  // CSR buckets (relation-major)
}

#define TILE_M 64
#define TILE_N 64
#define TILE_K 16

// C[M, 256] (+)= A[M, K] @ B[K, 256]  (+ bias when not accumulating)
__global__ __launch_bounds__(256)
void gemm_f32(const float* __restrict__ A, const float* __restrict__ B,
              const float* __restrict__ bias, float* __restrict__ C,
              int M, int K, int accumulate)
{
    __shared__ float As[TILE_K][TILE_M + 1];
    __shared__ float Bs[TILE_K][TILE_N + 1];
    const int tid = threadIdx.x;
    const int tx = tid & 15;   // N direction (4 cols each)
    const int ty = tid >> 4;   // M direction (4 rows each)
    const int row0 = blockIdx.y * TILE_M;
    const int col0 = blockIdx.x * TILE_N;

    float acc[4][4] = {};

    for (int k0 = 0; k0 < K; k0 += TILE_K) {
        for (int i = tid; i < TILE_M * TILE_K; i += 256) {
            int r = i >> 4;    // m
            int c = i & 15;    // k
            int gr = row0 + r;
            As[c][r] = (gr < M) ? A[(size_t)gr * K + (k0 + c)] : 0.0f;
        }
        for (int i = tid; i < TILE_K * TILE_N; i += 256) {
            int r = i >> 6;    // k
            int c = i & 63;    // n
            Bs[r][c] = B[(size_t)(k0 + r) * kH + (col0 + c)];
        }
        __syncthreads();
        #pragma unroll
        for (int kk = 0; kk < TILE_K; ++kk) {
            float a[4], b[4];
            #pragma unroll
            for (int i = 0; i < 4; ++i) a[i] = As[kk][ty * 4 + i];
            #pragma unroll
            for (int j = 0; j < 4; ++j) b[j] = Bs[kk][tx * 4 + j];
            #pragma unroll
            for (int i = 0; i < 4; ++i)
                #pragma unroll
                for (int j = 0; j < 4; ++j)
                    acc[i][j] += a[i] * b[j];
        }
        __syncthreads();
    }

    #pragma unroll
    for (int i = 0; i < 4; ++i) {
        int gr = row0 + ty * 4 + i;
        if (gr >= M) continue;
        #pragma unroll
        for (int j = 0; j < 4; ++j) {
            int gc = col0 + tx * 4 + j;
            size_t idx = (size_t)gr * kH + gc;
            if (accumulate) C[idx] += acc[i][j];
            else            C[idx] = acc[i][j] + (bias ? bias[gc] : 0.0f);
        }
    }
}

// ---------------- CSR build ----------------

__global__ __launch_bounds__(256)
void count_deg(const int* __restrict__ dst, int* __restrict__ deg, int nE)
{
    int e = blockIdx.x * 256 + threadIdx.x;
    if (e >= nE) return;
    int r = e / kER;
    atomicAdd(&deg[r * kN + dst[e]], 1);
}

// per-chunk (1024 buckets) sum
__global__ __launch_bounds__(256)
void chunk_reduce(const int* __restrict__ deg, int* __restrict__ chunkSum, int B)
{
    __shared__ int sm[256];
    int s = 0;
    #pragma unroll
    for (int j = 0; j < 4; ++j) {
        int idx = blockIdx.x * 1024 + j * 256 + threadIdx.x;
        if (idx < B) s += deg[idx];
    }
    sm[threadIdx.x] = s;
    __syncthreads();
    for (int o = 128; o >= 1; o >>= 1) {
        if (threadIdx.x < o) sm[threadIdx.x] += sm[threadIdx.x + o];
        __syncthreads();
    }
    if (threadIdx.x == 0) chunkSum[blockIdx.x] = sm[0];
}

// single-wave exclusive scan of chunk sums
__global__ __launch_bounds__(64)
void scan_chunks(const int* __restrict__ chunkSum, int* __restrict__ chunkBase, int n)
{
    int lane = threadIdx.x;
    int base = 0;
    for (int i0 = 0; i0 < n; i0 += 64) {
        int i = i0 + lane;
        int orig = (i < n) ? chunkSum[i] : 0;
        int v = orig;
        #pragma unroll
        for (int o = 1; o < 64; o <<= 1) {
            int t = __shfl_up(v, o);
            if (lane >= o) v += t;
        }
        if (i < n) chunkBase[i] = base + v - orig;
        base += __shfl(v, 63);
    }
}

// per-chunk exclusive scan (+ chunk base) -> off;  also writes off[B] sentinel
__global__ __launch_bounds__(256)
void scan_within(const int* __restrict__ deg, const int* __restrict__ chunkBase,
                 int* __restrict__ off, int B)
{
    __shared__ int ts[256];
    const int i0 = blockIdx.x * 1024;
    int v[4];
    int s = 0;
    #pragma unroll
    for (int j = 0; j < 4; ++j) {
        int idx = i0 + threadIdx.x * 4 + j;
        v[j] = (idx < B) ? deg[idx] : 0;
        s += v[j];
    }
    ts[threadIdx.x] = s;
    __syncthreads();
    for (int o = 1; o < 256; o <<= 1) {
        int u = (threadIdx.x >= o) ? ts[threadIdx.x - o] : 0;
        __syncthreads();
        ts[threadIdx.x] += u;
        __syncthreads();
    }
    int run = chunkBase[blockIdx.x] + ts[threadIdx.x] - s;  // exclusive base for this thread
    #pragma unroll
    for (int j = 0; j < 4; ++j) {
        int idx = i0 + threadIdx.x * 4 + j;
        if (idx <= B) off[idx] = run;
        run += v[j];
    }
}

__global__ __launch_bounds__(256)
void fill_csr(const int* __restrict__ src, const int* __restrict__ dst,
              int* __restrict__ cursor, int* __restrict__ esort, int nE)
{
    int e = blockIdx.x * 256 + threadIdx.x;
    if (e >= nE) return;
    int r = e / kER;
    int pos = atomicAdd(&cursor[r * kN + dst[e]], 1);
    esort[pos] = src[e];
}

// ---------------- aggregation (gather, atomic-free) ----------------

// one wave per dst node; all 4 relations; agg layout [N][4*256]
__global__ __launch_bounds__(256)
void aggregate4(const float* __restrict__ h, const int* __restrict__ off,
                const int* __restrict__ esort, float* __restrict__ agg)
{
    const int lane = threadIdx.x & 63;
    const int d = (int)((blockIdx.x * (size_t)blockDim.x + threadIdx.x) >> 6);
    if (d >= kN) return;
    float4 acc[4];
    #pragma unroll
    for (int r = 0; r < kR; ++r) acc[r] = make_float4(0.f, 0.f, 0.f, 0.f);
    #pragma unroll
    for (int r = 0; r < kR; ++r) {
        int b  = off[r * kN + d];
        int e2 = off[r * kN + d + 1];
        for (int t = b; t < e2; ++t) {
            int s = esort[t];
            float4 v = *reinterpret_cast<const float4*>(h + (size_t)s * kH + lane * 4);
            acc[r].x += v.x; acc[r].y += v.y; acc[r].z += v.z; acc[r].w += v.w;
        }
    }
    #pragma unroll
    for (int r = 0; r < kR; ++r)
        *reinterpret_cast<float4*>(agg + (size_t)d * (kR * kH) + r * kH + lane * 4) = acc[r];
}

// one wave per dst node; single relation; agg layout [N][256]
__global__ __launch_bounds__(256)
void aggregate1(const float* __restrict__ h, const int* __restrict__ off,
                const int* __restrict__ esort, float* __restrict__ agg)
{
    const int lane = threadIdx.x & 63;
    const int d = (int)((blockIdx.x * (size_t)blockDim.x + threadIdx.x) >> 6);
    if (d >= kN) return;
    float4 acc = make_float4(0.f, 0.f, 0.f, 0.f);
    int b  = off[d];
    int e2 = off[d + 1];
    for (int t = b; t < e2; ++t) {
        int s = esort[t];
        float4 v = *reinterpret_cast<const float4*>(h + (size_t)s * kH + lane * 4);
        acc.x += v.x; acc.y += v.y; acc.z += v.z; acc.w += v.w;
    }
    *reinterpret_cast<float4*>(agg + (size_t)d * kH + lane * 4) = acc;
}

// out_row = LN(xin_row [+ res_row]) * g + b    (one wave per row)
__global__ __launch_bounds__(256)
void ln_resid(const float* __restrict__ xin, const float* __restrict__ res,
              const float* __restrict__ g, const float* __restrict__ b,
              float* __restrict__ out, int nRows)
{
    const int lane = threadIdx.x & 63;
    const int row  = (int)((blockIdx.x * (size_t)blockDim.x + threadIdx.x) >> 6);
    if (row >= nRows) return;
    float4 v = *reinterpret_cast<const float4*>(xin + (size_t)row * kH + lane * 4);
    if (res) {
        float4 rr = *reinterpret_cast<const float4*>(res + (size_t)row * kH + lane * 4);
        v.x += rr.x; v.y += rr.y; v.z += rr.z; v.w += rr.w;
    }
    float s = v.x + v.y + v.z + v.w;
    #pragma unroll
    for (int o = 32; o >= 1; o >>= 1) s += __shfl_xor(s, o);
    const float mu = s * (1.0f / kH);
    const float dx = v.x - mu, dy = v.y - mu, dz = v.z - mu, dw = v.w - mu;
    float q = dx * dx + dy * dy + dz * dz + dw * dw;
    #pragma unroll
    for (int o = 32; o >= 1; o >>= 1) q += __shfl_xor(q, o);
    const float rstd = rsqrtf(q * (1.0f / kH) + 1e-5f);
    const float4 gg = *reinterpret_cast<const float4*>(g + lane * 4);
    const float4 bb = *reinterpret_cast<const float4*>(b + lane * 4);
    float4 o4;
    o4.x = dx * rstd * gg.x + bb.x;
    o4.y = dy * rstd * gg.y + bb.y;
    o4.z = dz * rstd * gg.z + bb.z;
    o4.w = dw * rstd * gg.w + bb.w;
    *reinterpret_cast<float4*>(out + (size_t)row * kH + lane * 4) = o4;
}

extern "C" void kernel_launch(void* const* d_in, const int* in_sizes, int n_in,
                              void* d_out, int out_size, void* d_ws, size_t ws_size,
                              hipStream_t stream)
{
    const float* x_c  = (const float*)d_in[0];
    const float* x_t  = (const float*)d_in[1];
    const float* x_d  = (const float*)d_in[2];
    const int*   ei   = (const int*)d_in[3];      // [2, R*E_R]
    const float* Wp_c = (const float*)d_in[4];
    const float* bp_c = (const float*)d_in[5];
    const float* Wp_t = (const float*)d_in[6];
    const float* bp_t = (const float*)d_in[7];
    const float* Wp_d = (const float*)d_in[8];
    const float* bp_d = (const float*)d_in[9];
    const float* rgcn_w    = (const float*)d_in[10]; // [2,4,256,256]
    const float* rgcn_root = (const float*)d_in[11]; // [2,256,256]
    const float* rgcn_b    = (const float*)d_in[12]; // [2,256]
    const float* ln_g = (const float*)d_in[13];      // [2,256]
    const float* ln_b = (const float*)d_in[14];      // [2,256]
    const float* Wo   = (const float*)d_in[15];      // [256,256]
    const float* bo   = (const float*)d_in[16];      // [256]

    const int* src_base = ei;                 // row 0
    const int* dst_base = ei + (size_t)kE;    // row 1

    const int nChunks = (kB + 1023) / 1024;   // 391

    // ---- workspace layout
    float* h = (float*)d_ws;                  // [N,256]
    // fused layout needs agg [N, 4*256]
    size_t fusedFloats = (size_t)kN * kH + (size_t)kN * kR * kH;
    size_t intWords    = (size_t)kB /*deg*/ + (size_t)(kB + 1) /*off*/
                       + (size_t)kE /*esort*/ + 2 * 1024 /*chunk*/ + 64;
    bool fused = ws_size >= (fusedFloats + /*align*/ 16) * sizeof(float) + intWords * sizeof(int);

    float* agg   = h + (size_t)kN * kH;       // [N, 4*256] or [N,256]
    float* fend  = agg + (fused ? (size_t)kN * kR * kH : (size_t)kN * kH);
    int* deg     = (int*)fend;                // [kB]   (reused as cursor)
    int* off     = deg + kB;                  // [kB+1]
    int* esort   = off + (kB + 1);            // [kE]
    int* chunkS  = esort + kE;                // [nChunks]
    int* chunkB  = chunkS + 1024;             // [nChunks]

    float* out = (float*)d_out;               // [N,256] (layer scratch + final y)

    const dim3 blk(256);

    // ---- CSR build (once per call)
    hipMemsetAsync(deg, 0, (size_t)kB * sizeof(int), stream);
    count_deg<<<dim3((kE + 255) / 256), blk, 0, stream>>>(dst_base, deg, kE);
    chunk_reduce<<<dim3(nChunks), blk, 0, stream>>>(deg, chunkS, kB);
    scan_chunks<<<dim3(1), dim3(64), 0, stream>>>(chunkS, chunkB, nChunks);
    scan_within<<<dim3(nChunks), blk, 0, stream>>>(deg, chunkB, off, kB);
    hipMemcpyAsync(deg, off, (size_t)kB * sizeof(int), hipMemcpyDeviceToDevice, stream);
    fill_csr<<<dim3((kE + 255) / 256), blk, 0, stream>>>(src_base, dst_base, deg, esort, kE);

    // ---- projections: h = concat(x_c@Wp_c+b, x_t@Wp_t+b, x_d@Wp_d+b)
    {
        dim3 g1(kH / TILE_N, (kNC + TILE_M - 1) / TILE_M);
        gemm_f32<<<g1, blk, 0, stream>>>(x_c, Wp_c, bp_c, h, kNC, 256, 0);
        dim3 g2(kH / TILE_N, (kNT + TILE_M - 1) / TILE_M);
        gemm_f32<<<g2, blk, 0, stream>>>(x_t, Wp_t, bp_t, h + (size_t)kNC * kH, kNT, 512, 0);
        dim3 g3(kH / TILE_N, (kND + TILE_M - 1) / TILE_M);
        gemm_f32<<<g3, blk, 0, stream>>>(x_d, Wp_d, bp_d, h + (size_t)(kNC + kNT) * kH, kND, 128, 0);
    }

    const dim3 gemmN(kH / TILE_N, (kN + TILE_M - 1) / TILE_M);
    const dim3 aggGrid((int)(((size_t)kN * 64 + 255) / 256));

    for (int l = 0; l < 2; ++l) {
        if (fused) {
            // agg[d] = [seg_r0 | seg_r1 | seg_r2 | seg_r3] of raw h
            aggregate4<<<aggGrid, blk, 0, stream>>>(h, off, esort, agg);
            // out = agg @ rgcn_w[l]  (K=1024; rgcn_w[l] is [1024,256] row-major) + b
            gemm_f32<<<gemmN, blk, 0, stream>>>(agg, rgcn_w + (size_t)l * kR * kH * kH,
                                                rgcn_b + (size_t)l * kH, out, kN, kR * kH, 0);
            // out += h @ root[l]
            gemm_f32<<<gemmN, blk, 0, stream>>>(h, rgcn_root + (size_t)l * kH * kH,
                                                nullptr, out, kN, kH, 1);
        } else {
            gemm_f32<<<gemmN, blk, 0, stream>>>(h, rgcn_root + (size_t)l * kH * kH,
                                                rgcn_b + (size_t)l * kH, out, kN, kH, 0);
            for (int r = 0; r < kR; ++r) {
                aggregate1<<<aggGrid, blk, 0, stream>>>(h, off + (size_t)r * kN, esort, agg);
                gemm_f32<<<gemmN, blk, 0, stream>>>(
                    agg, rgcn_w + (size_t)(l * kR + r) * kH * kH, nullptr, out, kN, kH, 1);
            }
        }
        // h = LN(out [+ h]) * g[l] + b[l]
        ln_resid<<<dim3((int)(((size_t)kN * 64 + 255) / 256)), blk, 0, stream>>>(
            out, (l > 0) ? h : nullptr, ln_g + (size_t)l * kH, ln_b + (size_t)l * kH, h, kN);
    }

    // y = h @ Wo + bo  -> d_out
    gemm_f32<<<gemmN, blk, 0, stream>>>(h, Wo, bo, out, kN, kH, 0);
}

// Round 3
// 1206.035 us; speedup vs baseline: 12.5100x; 4.1354x over previous
//
#include <hip/hip_runtime.h>
#include <hip/hip_bf16.h>

namespace {
constexpr int kNC = 50000;
constexpr int kNT = 30000;
constexpr int kND = 20000;
constexpr int kN  = 100000;   // total nodes
constexpr int kR  = 4;        // relations
constexpr int kER = 400000;   // edges per relation
constexpr int kE  = kR * kER; // 1.6M edges
constexpr int kH  = 256;      // hidden dim
constexpr int kB  = kR * kN;  // CSR buckets (relation-major)

constexpr int padM(int m) { return (m + 127) / 128 * 128; }
}

typedef __attribute__((ext_vector_type(8))) short short8;
typedef __attribute__((ext_vector_type(4))) float f32x4;

__device__ __forceinline__ unsigned short f2bf(float x) {
    unsigned u = __builtin_bit_cast(unsigned, x);
    u += 0x7FFF + ((u >> 16) & 1);      // RNE
    return (unsigned short)(u >> 16);
}
__device__ __forceinline__ float bf2f(unsigned short u) {
    unsigned v = ((unsigned)u) << 16;
    return __builtin_bit_cast(float, v);
}

__device__ __forceinline__ void gld16(const void* src, void* lds) {
    __builtin_amdgcn_global_load_lds(
        (const __attribute__((address_space(1))) void*)src,
        (__attribute__((address_space(3))) void*)lds, 16, 0, 0);
}

// ------------------------------------------------------------------
// bf16 MFMA GEMM:  C[M,256] = A[M,K](bf16) @ Bt[256,K]^T(bf16) + bias
// 128x128 tile, BK=32, 4 waves (2x2), global_load_lds staging with
// bijective slot swizzle  s_lds = s_g ^ ((row>>1)&3)  (2-way max on read).
// Output: bf16 (Cb) or f32 (Cf), optional f32 accumulate.
// ------------------------------------------------------------------
__global__ __launch_bounds__(256)
void gemm_mfma(const unsigned short* __restrict__ A, int lda,
               const unsigned short* __restrict__ Bt, int ldb,
               const float* __restrict__ bias,
               float* __restrict__ Cf, unsigned short* __restrict__ Cb,
               int M, int K, int accumulate)
{
    __shared__ __attribute__((aligned(16))) unsigned short As[128 * 32];
    __shared__ __attribute__((aligned(16))) unsigned short Bs[128 * 32];
    const int tid  = threadIdx.x;
    const int lane = tid & 63;
    const int wid  = tid >> 6;
    const int wm   = wid >> 1;
    const int wn   = wid & 1;
    const int row0 = blockIdx.y * 128;
    const int col0 = blockIdx.x * 128;

    const int cr = lane >> 2;   // row within 16-row chunk
    const int cs = lane & 3;    // lds 16B-slot within row

    const f32x4 z4 = {0.f, 0.f, 0.f, 0.f};
    f32x4 acc[4][4];
    #pragma unroll
    for (int m = 0; m < 4; ++m)
        #pragma unroll
        for (int n = 0; n < 4; ++n) acc[m][n] = z4;

    const int fr = lane & 15;   // fragment row/col
    const int kb = lane >> 4;   // k-block (8 elems)

    for (int k0 = 0; k0 < K; k0 += 32) {
        #pragma unroll
        for (int j = 0; j < 2; ++j) {
            const int chunk = wid * 2 + j;
            const int r  = chunk * 16 + cr;
            const int sg = cs ^ ((r >> 1) & 3);
            gld16(A  + (size_t)(row0 + r) * lda + k0 + sg * 8, As + chunk * 512);
            gld16(Bt + (size_t)(col0 + r) * ldb + k0 + sg * 8, Bs + chunk * 512);
        }
        __syncthreads();
        short8 a[4], b[4];
        #pragma unroll
        for (int m = 0; m < 4; ++m) {
            const int am = wm * 64 + m * 16 + fr;
            const int s  = kb ^ ((am >> 1) & 3);
            a[m] = *(const short8*)(As + am * 32 + s * 8);
        }
        #pragma unroll
        for (int n = 0; n < 4; ++n) {
            const int bn = wn * 64 + n * 16 + fr;
            const int s  = kb ^ ((bn >> 1) & 3);
            b[n] = *(const short8*)(Bs + bn * 32 + s * 8);
        }
        #pragma unroll
        for (int m = 0; m < 4; ++m)
            #pragma unroll
            for (int n = 0; n < 4; ++n)
                acc[m][n] = __builtin_amdgcn_mfma_f32_16x16x32_bf16(
                    a[m], b[n], acc[m][n], 0, 0, 0);
        __syncthreads();
    }

    const int fq = lane >> 4;
    #pragma unroll
    for (int m = 0; m < 4; ++m) {
        #pragma unroll
        for (int n = 0; n < 4; ++n) {
            const int col  = col0 + wn * 64 + n * 16 + fr;
            const int rowb = row0 + wm * 64 + m * 16 + fq * 4;
            const float bv = bias ? bias[col] : 0.0f;
            #pragma unroll
            for (int i = 0; i < 4; ++i) {
                const int row = rowb + i;
                if (row >= M) continue;
                const float v = acc[m][n][i] + bv;
                const size_t idx = (size_t)row * kH + col;
                if (Cb) Cb[idx] = f2bf(v);
                else if (accumulate) Cf[idx] += v;
                else Cf[idx] = v;
            }
        }
    }
}

// ---------------- dtype prep ----------------

__global__ __launch_bounds__(256)
void conv_bf16(const float* __restrict__ in, unsigned short* __restrict__ out, int n)
{
    int i = (blockIdx.x * 256 + threadIdx.x) * 4;
    if (i >= n) return;
    float4 v = *reinterpret_cast<const float4*>(in + i);
    ushort4 o = { f2bf(v.x), f2bf(v.y), f2bf(v.z), f2bf(v.w) };
    *reinterpret_cast<ushort4*>(out + i) = o;
}

// W [K][256] f32 -> Wt [256][K] bf16
__global__ __launch_bounds__(256)
void wT_bf16(const float* __restrict__ W, unsigned short* __restrict__ Wt, int K)
{
    int t = blockIdx.x * 256 + threadIdx.x;
    if (t >= 256 * K) return;
    int c = t / K, k = t % K;
    Wt[t] = f2bf(W[(size_t)k * 256 + c]);
}

// [w(4x256x256); root(256x256)] -> Wt [256][1280] bf16
__global__ __launch_bounds__(256)
void wstack_bf16(const float* __restrict__ w, const float* __restrict__ root,
                 unsigned short* __restrict__ Wt)
{
    int t = blockIdx.x * 256 + threadIdx.x;
    if (t >= 256 * 1280) return;
    int c = t / 1280, k = t % 1280;
    float v = (k < 1024) ? w[(size_t)((k >> 8) * 256 + (k & 255)) * 256 + c]
                         : root[(size_t)(k - 1024) * 256 + c];
    Wt[t] = f2bf(v);
}

// ---------------- CSR build ----------------

__global__ __launch_bounds__(256)
void count_deg(const int* __restrict__ dst, int* __restrict__ deg, int nE)
{
    int e = blockIdx.x * 256 + threadIdx.x;
    if (e >= nE) return;
    int r = e / kER;
    atomicAdd(&deg[r * kN + dst[e]], 1);
}

__global__ __launch_bounds__(256)
void chunk_reduce(const int* __restrict__ deg, int* __restrict__ chunkSum, int B)
{
    __shared__ int sm[256];
    int s = 0;
    #pragma unroll
    for (int j = 0; j < 4; ++j) {
        int idx = blockIdx.x * 1024 + j * 256 + threadIdx.x;
        if (idx < B) s += deg[idx];
    }
    sm[threadIdx.x] = s;
    __syncthreads();
    for (int o = 128; o >= 1; o >>= 1) {
        if (threadIdx.x < o) sm[threadIdx.x] += sm[threadIdx.x + o];
        __syncthreads();
    }
    if (threadIdx.x == 0) chunkSum[blockIdx.x] = sm[0];
}

__global__ __launch_bounds__(64)
void scan_chunks(const int* __restrict__ chunkSum, int* __restrict__ chunkBase, int n)
{
    int lane = threadIdx.x;
    int base = 0;
    for (int i0 = 0; i0 < n; i0 += 64) {
        int i = i0 + lane;
        int orig = (i < n) ? chunkSum[i] : 0;
        int v = orig;
        #pragma unroll
        for (int o = 1; o < 64; o <<= 1) {
            int t = __shfl_up(v, o);
            if (lane >= o) v += t;
        }
        if (i < n) chunkBase[i] = base + v - orig;
        base += __shfl(v, 63);
    }
}

__global__ __launch_bounds__(256)
void scan_within(const int* __restrict__ deg, const int* __restrict__ chunkBase,
                 int* __restrict__ off, int B)
{
    __shared__ int ts[256];
    const int i0 = blockIdx.x * 1024;
    int v[4];
    int s = 0;
    #pragma unroll
    for (int j = 0; j < 4; ++j) {
        int idx = i0 + threadIdx.x * 4 + j;
        v[j] = (idx < B) ? deg[idx] : 0;
        s += v[j];
    }
    ts[threadIdx.x] = s;
    __syncthreads();
    for (int o = 1; o < 256; o <<= 1) {
        int u = (threadIdx.x >= o) ? ts[threadIdx.x - o] : 0;
        __syncthreads();
        ts[threadIdx.x] += u;
        __syncthreads();
    }
    int run = chunkBase[blockIdx.x] + ts[threadIdx.x] - s;
    #pragma unroll
    for (int j = 0; j < 4; ++j) {
        int idx = i0 + threadIdx.x * 4 + j;
        if (idx <= B) off[idx] = run;
        run += v[j];
    }
}

__global__ __launch_bounds__(256)
void fill_csr(const int* __restrict__ src, const int* __restrict__ dst,
              int* __restrict__ cursor, int* __restrict__ esort, int nE)
{
    int e = blockIdx.x * 256 + threadIdx.x;
    if (e >= nE) return;
    int r = e / kER;
    int pos = atomicAdd(&cursor[r * kN + dst[e]], 1);
    esort[pos] = src[e];
}

// ---------------- aggregation ----------------

// one wave per dst; agg[N][1280] bf16 = [4 relation segsums | own h row]
__global__ __launch_bounds__(256)
void aggregate5(const unsigned short* __restrict__ h, const int* __restrict__ off,
                const int* __restrict__ esort, unsigned short* __restrict__ agg)
{
    const int lane = threadIdx.x & 63;
    const int d = (int)((blockIdx.x * (size_t)blockDim.x + threadIdx.x) >> 6);
    if (d >= kN) return;
    const int c0 = lane * 4;
    #pragma unroll
    for (int r = 0; r < kR; ++r) {
        float a0 = 0.f, a1 = 0.f, a2 = 0.f, a3 = 0.f;
        const int b  = off[r * kN + d];
        const int e2 = off[r * kN + d + 1];
        for (int t = b; t < e2; ++t) {
            const int s = esort[t];
            ushort4 v = *reinterpret_cast<const ushort4*>(h + (size_t)s * kH + c0);
            a0 += bf2f(v.x); a1 += bf2f(v.y); a2 += bf2f(v.z); a3 += bf2f(v.w);
        }
        ushort4 o = { f2bf(a0), f2bf(a1), f2bf(a2), f2bf(a3) };
        *reinterpret_cast<ushort4*>(agg + (size_t)d * 1280 + r * kH + c0) = o;
    }
    ushort4 own = *reinterpret_cast<const ushort4*>(h + (size_t)d * kH + c0);
    *reinterpret_cast<ushort4*>(agg + (size_t)d * 1280 + 1024 + c0) = own;
}

// fallback: one relation, agg[N][256] bf16
__global__ __launch_bounds__(256)
void aggregate1_bf(const unsigned short* __restrict__ h, const int* __restrict__ off,
                   const int* __restrict__ esort, unsigned short* __restrict__ agg)
{
    const int lane = threadIdx.x & 63;
    const int d = (int)((blockIdx.x * (size_t)blockDim.x + threadIdx.x) >> 6);
    if (d >= kN) return;
    const int c0 = lane * 4;
    float a0 = 0.f, a1 = 0.f, a2 = 0.f, a3 = 0.f;
    const int b  = off[d];
    const int e2 = off[d + 1];
    for (int t = b; t < e2; ++t) {
        const int s = esort[t];
        ushort4 v = *reinterpret_cast<const ushort4*>(h + (size_t)s * kH + c0);
        a0 += bf2f(v.x); a1 += bf2f(v.y); a2 += bf2f(v.z); a3 += bf2f(v.w);
    }
    ushort4 o = { f2bf(a0), f2bf(a1), f2bf(a2), f2bf(a3) };
    *reinterpret_cast<ushort4*>(agg + (size_t)d * kH + c0) = o;
}

// h_bf16 = LN(xin_f32 [+ res_bf16]) * g + b   (one wave per row)
__global__ __launch_bounds__(256)
void ln_resid_bf(const float* __restrict__ xin, const unsigned short* __restrict__ res,
                 const float* __restrict__ g, const float* __restrict__ b,
                 unsigned short* __restrict__ out, int nRows)
{
    const int lane = threadIdx.x & 63;
    const int row  = (int)((blockIdx.x * (size_t)blockDim.x + threadIdx.x) >> 6);
    if (row >= nRows) return;
    float4 v = *reinterpret_cast<const float4*>(xin + (size_t)row * kH + lane * 4);
    if (res) {
        ushort4 rr = *reinterpret_cast<const ushort4*>(res + (size_t)row * kH + lane * 4);
        v.x += bf2f(rr.x); v.y += bf2f(rr.y); v.z += bf2f(rr.z); v.w += bf2f(rr.w);
    }
    float s = v.x + v.y + v.z + v.w;
    #pragma unroll
    for (int o = 32; o >= 1; o >>= 1) s += __shfl_xor(s, o);
    const float mu = s * (1.0f / kH);
    const float dx = v.x - mu, dy = v.y - mu, dz = v.z - mu, dw = v.w - mu;
    float q = dx * dx + dy * dy + dz * dz + dw * dw;
    #pragma unroll
    for (int o = 32; o >= 1; o >>= 1) q += __shfl_xor(q, o);
    const float rstd = rsqrtf(q * (1.0f / kH) + 1e-5f);
    const float4 gg = *reinterpret_cast<const float4*>(g + lane * 4);
    const float4 bb = *reinterpret_cast<const float4*>(b + lane * 4);
    ushort4 o4;
    o4.x = f2bf(dx * rstd * gg.x + bb.x);
    o4.y = f2bf(dy * rstd * gg.y + bb.y);
    o4.z = f2bf(dz * rstd * gg.z + bb.z);
    o4.w = f2bf(dw * rstd * gg.w + bb.w);
    *reinterpret_cast<ushort4*>(out + (size_t)row * kH + lane * 4) = o4;
}

// ------------------------------------------------------------------

extern "C" void kernel_launch(void* const* d_in, const int* in_sizes, int n_in,
                              void* d_out, int out_size, void* d_ws, size_t ws_size,
                              hipStream_t stream)
{
    const float* x_c  = (const float*)d_in[0];
    const float* x_t  = (const float*)d_in[1];
    const float* x_d  = (const float*)d_in[2];
    const int*   ei   = (const int*)d_in[3];
    const float* Wp_c = (const float*)d_in[4];
    const float* bp_c = (const float*)d_in[5];
    const float* Wp_t = (const float*)d_in[6];
    const float* bp_t = (const float*)d_in[7];
    const float* Wp_d = (const float*)d_in[8];
    const float* bp_d = (const float*)d_in[9];
    const float* rgcn_w    = (const float*)d_in[10];
    const float* rgcn_root = (const float*)d_in[11];
    const float* rgcn_b    = (const float*)d_in[12];
    const float* ln_g = (const float*)d_in[13];
    const float* ln_b = (const float*)d_in[14];
    const float* Wo   = (const float*)d_in[15];
    const float* bo   = (const float*)d_in[16];

    const int* src_base = ei;
    const int* dst_base = ei + (size_t)kE;

    const int nChunks = (kB + 1023) / 1024;
    const int pN  = padM(kN);    // 100096
    const int pNC = padM(kNC);   // 50048
    const int pNT = padM(kNT);   // 30080
    const int pND = padM(kND);   // 20096

    // ---- workspace carve
    char* p = (char*)d_ws;
    unsigned short* h_bf = (unsigned short*)p;  p += (size_t)pN * kH * 2;

    const size_t aggBytesFused = (size_t)pN * 1280 * 2;
    const size_t aggBytesSmall = (size_t)pN * kH * 2;
    const size_t xBytes = ((size_t)pNC * 256 + (size_t)pNT * 512 + (size_t)pND * 128) * 2;
    const size_t wBytes = ((size_t)256 * 256 + 256 * 512 + 256 * 128 +
                           2 * 256 * 1280 + 256 * 256) * 2;
    const size_t iBytes = ((size_t)kB + (kB + 1) + kE + 2048 + 64) * 4;

    const bool fused = ws_size >= (size_t)pN * kH * 2 + aggBytesFused + wBytes + iBytes + 256;

    unsigned short* agg = (unsigned short*)p;
    unsigned short* xbf_c;
    unsigned short* xbf_t;
    unsigned short* xbf_d;
    if (fused) {
        p += aggBytesFused;          // x aliases inside agg (used before layers)
        xbf_c = agg;
        xbf_t = xbf_c + (size_t)pNC * 256;
        xbf_d = xbf_t + (size_t)pNT * 512;
    } else {
        p += aggBytesSmall;
        xbf_c = (unsigned short*)p;  p += xBytes;   // separate region
        xbf_t = xbf_c + (size_t)pNC * 256;
        xbf_d = xbf_t + (size_t)pNT * 512;
    }
    unsigned short* Wt_c = (unsigned short*)p;          // [256][256]
    unsigned short* Wt_t = Wt_c + 256 * 256;            // [256][512]
    unsigned short* Wt_d = Wt_t + 256 * 512;            // [256][128]
    unsigned short* Wst  = Wt_d + 256 * 128;            // [2][256][1280]
    unsigned short* Wt_o = Wst + 2 * 256 * 1280;        // [256][256]
    p = (char*)(Wt_o + 256 * 256);

    int* deg    = (int*)p;
    int* off    = deg + kB;
    int* esort  = off + (kB + 1);
    int* chunkS = esort + kE;
    int* chunkB = chunkS + 1024;

    float* outf = (float*)d_out;   // [N,256] f32: layer scratch + final y

    const dim3 blk(256);

    // ---- CSR build
    hipMemsetAsync(deg, 0, (size_t)kB * sizeof(int), stream);
    count_deg<<<dim3((kE + 255) / 256), blk, 0, stream>>>(dst_base, deg, kE);
    chunk_reduce<<<dim3(nChunks), blk, 0, stream>>>(deg, chunkS, kB);
    scan_chunks<<<dim3(1), dim3(64), 0, stream>>>(chunkS, chunkB, nChunks);
    scan_within<<<dim3(nChunks), blk, 0, stream>>>(deg, chunkB, off, kB);
    hipMemcpyAsync(deg, off, (size_t)kB * sizeof(int), hipMemcpyDeviceToDevice, stream);
    fill_csr<<<dim3((kE + 255) / 256), blk, 0, stream>>>(src_base, dst_base, deg, esort, kE);

    // ---- dtype prep
    conv_bf16<<<dim3((kNC * 256 / 4 + 255) / 256), blk, 0, stream>>>(x_c, xbf_c, kNC * 256);
    conv_bf16<<<dim3((kNT * 512 / 4 + 255) / 256), blk, 0, stream>>>(x_t, xbf_t, kNT * 512);
    conv_bf16<<<dim3((kND * 128 / 4 + 255) / 256), blk, 0, stream>>>(x_d, xbf_d, kND * 128);
    wT_bf16<<<dim3((256 * 256 + 255) / 256), blk, 0, stream>>>(Wp_c, Wt_c, 256);
    wT_bf16<<<dim3((256 * 512 + 255) / 256), blk, 0, stream>>>(Wp_t, Wt_t, 512);
    wT_bf16<<<dim3((256 * 128 + 255) / 256), blk, 0, stream>>>(Wp_d, Wt_d, 128);
    wT_bf16<<<dim3((256 * 256 + 255) / 256), blk, 0, stream>>>(Wo, Wt_o, 256);
    for (int l = 0; l < 2; ++l)
        wstack_bf16<<<dim3((256 * 1280 + 255) / 256), blk, 0, stream>>>(
            rgcn_w + (size_t)l * kR * kH * kH, rgcn_root + (size_t)l * kH * kH,
            Wst + (size_t)l * 256 * 1280);

    // ---- projections -> h_bf
    gemm_mfma<<<dim3(2, pNC / 128), blk, 0, stream>>>(
        xbf_c, 256, Wt_c, 256, bp_c, nullptr, h_bf, kNC, 256, 0);
    gemm_mfma<<<dim3(2, pNT / 128), blk, 0, stream>>>(
        xbf_t, 512, Wt_t, 512, bp_t, nullptr, h_bf + (size_t)kNC * kH, kNT, 512, 0);
    gemm_mfma<<<dim3(2, pND / 128), blk, 0, stream>>>(
        xbf_d, 128, Wt_d, 128, bp_d, nullptr, h_bf + (size_t)(kNC + kNT) * kH, kND, 128, 0);

    const dim3 gemmN(2, pN / 128);
    const dim3 waveGrid((int)(((size_t)kN * 64 + 255) / 256));

    for (int l = 0; l < 2; ++l) {
        if (fused) {
            aggregate5<<<waveGrid, blk, 0, stream>>>(h_bf, off, esort, agg);
            gemm_mfma<<<gemmN, blk, 0, stream>>>(
                agg, 1280, Wst + (size_t)l * 256 * 1280, 1280,
                rgcn_b + (size_t)l * kH, outf, nullptr, kN, 1280, 0);
        } else {
            // root first (with bias), then 4 relation accumulates
            gemm_mfma<<<gemmN, blk, 0, stream>>>(
                h_bf, 256, Wst + (size_t)l * 256 * 1280 + 1024, 1280,
                rgcn_b + (size_t)l * kH, outf, nullptr, kN, 256, 0);
            for (int r = 0; r < kR; ++r) {
                aggregate1_bf<<<waveGrid, blk, 0, stream>>>(h_bf, off + (size_t)r * kN, esort, agg);
                gemm_mfma<<<gemmN, blk, 0, stream>>>(
                    agg, 256, Wst + (size_t)l * 256 * 1280 + (size_t)r * 256, 1280,
                    nullptr, outf, nullptr, kN, 256, 1);
            }
        }
        ln_resid_bf<<<waveGrid, blk, 0, stream>>>(
            outf, (l > 0) ? h_bf : nullptr, ln_g + (size_t)l * kH, ln_b + (size_t)l * kH,
            h_bf, kN);
    }

    // ---- final: y = h @ Wo + bo -> d_out (f32)
    gemm_mfma<<<gemmN, blk, 0, stream>>>(
        h_bf, 256, Wt_o, 256, bo, outf, nullptr, kN, 256, 0);
}

// Round 5
// 1154.753 us; speedup vs baseline: 13.0655x; 1.0444x over previous
//
#include <hip/hip_runtime.h>
#include <hip/hip_bf16.h>

namespace {
constexpr int kNC = 50000;
constexpr int kNT = 30000;
constexpr int kND = 20000;
constexpr int kN  = 100000;   // total nodes
constexpr int kR  = 4;        // relations
constexpr int kER = 400000;   // edges per relation
constexpr int kE  = kR * kER; // 1.6M edges
constexpr int kH  = 256;      // hidden dim
constexpr int kB  = kR * kN;  // CSR buckets (relation-major)

constexpr int padM(int m) { return (m + 127) / 128 * 128; }
}

typedef __attribute__((ext_vector_type(8))) short short8;
typedef __attribute__((ext_vector_type(4))) float f32x4;
typedef __attribute__((ext_vector_type(4))) unsigned short us4;

__device__ __forceinline__ unsigned short f2bf(float x) {
    unsigned u = __builtin_bit_cast(unsigned, x);
    u += 0x7FFF + ((u >> 16) & 1);      // RNE
    return (unsigned short)(u >> 16);
}
__device__ __forceinline__ float bf2f(unsigned short u) {
    unsigned v = ((unsigned)u) << 16;
    return __builtin_bit_cast(float, v);
}

__device__ __forceinline__ void gld16(const void* src, void* lds) {
    __builtin_amdgcn_global_load_lds(
        (const __attribute__((address_space(1))) void*)src,
        (__attribute__((address_space(3))) void*)lds, 16, 0, 0);
}

__device__ __forceinline__ void nt_store_u4(unsigned short* p, us4 v) {
    __builtin_nontemporal_store(v, reinterpret_cast<us4*>(p));
}
__device__ __forceinline__ us4 ld_u4(const unsigned short* p) {
    return *reinterpret_cast<const us4*>(p);
}
__device__ __forceinline__ void nt_store_f(float* p, float v) {
    __builtin_nontemporal_store(v, p);
}
__device__ __forceinline__ f32x4 nt_load_f4(const float* p) {
    return __builtin_nontemporal_load(reinterpret_cast<const f32x4*>(p));
}

// ------------------------------------------------------------------
// bf16 MFMA GEMM:  C[M,256] = A[M,K](bf16) @ Bt[256,K]^T(bf16) + bias
// 128x128 tile, BK=32, 4 waves (2x2), global_load_lds staging with
// bijective slot swizzle  s_lds = s_g ^ ((row>>1)&3)  (2-way max on read).
// Output: bf16 (Cb) or f32 (Cf, nt-stored), optional f32 accumulate.
// ------------------------------------------------------------------
__global__ __launch_bounds__(256)
void gemm_mfma(const unsigned short* __restrict__ A, int lda,
               const unsigned short* __restrict__ Bt, int ldb,
               const float* __restrict__ bias,
               float* __restrict__ Cf, unsigned short* __restrict__ Cb,
               int M, int K, int accumulate)
{
    __shared__ __attribute__((aligned(16))) unsigned short As[128 * 32];
    __shared__ __attribute__((aligned(16))) unsigned short Bs[128 * 32];
    const int tid  = threadIdx.x;
    const int lane = tid & 63;
    const int wid  = tid >> 6;
    const int wm   = wid >> 1;
    const int wn   = wid & 1;
    const int row0 = blockIdx.y * 128;
    const int col0 = blockIdx.x * 128;

    const int cr = lane >> 2;   // row within 16-row chunk
    const int cs = lane & 3;    // lds 16B-slot within row

    const f32x4 z4 = {0.f, 0.f, 0.f, 0.f};
    f32x4 acc[4][4];
    #pragma unroll
    for (int m = 0; m < 4; ++m)
        #pragma unroll
        for (int n = 0; n < 4; ++n) acc[m][n] = z4;

    const int fr = lane & 15;   // fragment row/col
    const int kb = lane >> 4;   // k-block (8 elems)

    for (int k0 = 0; k0 < K; k0 += 32) {
        #pragma unroll
        for (int j = 0; j < 2; ++j) {
            const int chunk = wid * 2 + j;
            const int r  = chunk * 16 + cr;
            const int sg = cs ^ ((r >> 1) & 3);
            gld16(A  + (size_t)(row0 + r) * lda + k0 + sg * 8, As + chunk * 512);
            gld16(Bt + (size_t)(col0 + r) * ldb + k0 + sg * 8, Bs + chunk * 512);
        }
        __syncthreads();
        short8 a[4], b[4];
        #pragma unroll
        for (int m = 0; m < 4; ++m) {
            const int am = wm * 64 + m * 16 + fr;
            const int s  = kb ^ ((am >> 1) & 3);
            a[m] = *(const short8*)(As + am * 32 + s * 8);
        }
        #pragma unroll
        for (int n = 0; n < 4; ++n) {
            const int bn = wn * 64 + n * 16 + fr;
            const int s  = kb ^ ((bn >> 1) & 3);
            b[n] = *(const short8*)(Bs + bn * 32 + s * 8);
        }
        #pragma unroll
        for (int m = 0; m < 4; ++m)
            #pragma unroll
            for (int n = 0; n < 4; ++n)
                acc[m][n] = __builtin_amdgcn_mfma_f32_16x16x32_bf16(
                    a[m], b[n], acc[m][n], 0, 0, 0);
        __syncthreads();
    }

    const int fq = lane >> 4;
    #pragma unroll
    for (int m = 0; m < 4; ++m) {
        #pragma unroll
        for (int n = 0; n < 4; ++n) {
            const int col  = col0 + wn * 64 + n * 16 + fr;
            const int rowb = row0 + wm * 64 + m * 16 + fq * 4;
            const float bv = bias ? bias[col] : 0.0f;
            #pragma unroll
            for (int i = 0; i < 4; ++i) {
                const int row = rowb + i;
                if (row >= M) continue;
                const float v = acc[m][n][i] + bv;
                const size_t idx = (size_t)row * kH + col;
                if (Cb) Cb[idx] = f2bf(v);
                else if (accumulate) Cf[idx] += v;
                else nt_store_f(&Cf[idx], v);
            }
        }
    }
}

// ---------------- dtype prep ----------------

__global__ __launch_bounds__(256)
void conv_bf16(const float* __restrict__ in, unsigned short* __restrict__ out, int n)
{
    int i = (blockIdx.x * 256 + threadIdx.x) * 4;
    if (i >= n) return;
    f32x4 v = *reinterpret_cast<const f32x4*>(in + i);
    us4 o = { f2bf(v.x), f2bf(v.y), f2bf(v.z), f2bf(v.w) };
    *reinterpret_cast<us4*>(out + i) = o;
}

// W [K][256] f32 -> Wt [256][K] bf16
__global__ __launch_bounds__(256)
void wT_bf16(const float* __restrict__ W, unsigned short* __restrict__ Wt, int K)
{
    int t = blockIdx.x * 256 + threadIdx.x;
    if (t >= 256 * K) return;
    int c = t / K, k = t % K;
    Wt[t] = f2bf(W[(size_t)k * 256 + c]);
}

// [w(4x256x256); root(256x256)] -> Wt [256][1280] bf16
__global__ __launch_bounds__(256)
void wstack_bf16(const float* __restrict__ w, const float* __restrict__ root,
                 unsigned short* __restrict__ Wt)
{
    int t = blockIdx.x * 256 + threadIdx.x;
    if (t >= 256 * 1280) return;
    int c = t / 1280, k = t % 1280;
    float v = (k < 1024) ? w[(size_t)((k >> 8) * 256 + (k & 255)) * 256 + c]
                         : root[(size_t)(k - 1024) * 256 + c];
    Wt[t] = f2bf(v);
}

// ---------------- CSR build ----------------

__global__ __launch_bounds__(256)
void count_deg(const int* __restrict__ dst, int* __restrict__ deg, int nE)
{
    int e = blockIdx.x * 256 + threadIdx.x;
    if (e >= nE) return;
    int r = e / kER;
    atomicAdd(&deg[r * kN + dst[e]], 1);
}

__global__ __launch_bounds__(256)
void chunk_reduce(const int* __restrict__ deg, int* __restrict__ chunkSum, int B)
{
    __shared__ int sm[256];
    int s = 0;
    #pragma unroll
    for (int j = 0; j < 4; ++j) {
        int idx = blockIdx.x * 1024 + j * 256 + threadIdx.x;
        if (idx < B) s += deg[idx];
    }
    sm[threadIdx.x] = s;
    __syncthreads();
    for (int o = 128; o >= 1; o >>= 1) {
        if (threadIdx.x < o) sm[threadIdx.x] += sm[threadIdx.x + o];
        __syncthreads();
    }
    if (threadIdx.x == 0) chunkSum[blockIdx.x] = sm[0];
}

__global__ __launch_bounds__(64)
void scan_chunks(const int* __restrict__ chunkSum, int* __restrict__ chunkBase, int n)
{
    int lane = threadIdx.x;
    int base = 0;
    for (int i0 = 0; i0 < n; i0 += 64) {
        int i = i0 + lane;
        int orig = (i < n) ? chunkSum[i] : 0;
        int v = orig;
        #pragma unroll
        for (int o = 1; o < 64; o <<= 1) {
            int t = __shfl_up(v, o);
            if (lane >= o) v += t;
        }
        if (i < n) chunkBase[i] = base + v - orig;
        base += __shfl(v, 63);
    }
}

__global__ __launch_bounds__(256)
void scan_within(const int* __restrict__ deg, const int* __restrict__ chunkBase,
                 int* __restrict__ off, int B)
{
    __shared__ int ts[256];
    const int i0 = blockIdx.x * 1024;
    int v[4];
    int s = 0;
    #pragma unroll
    for (int j = 0; j < 4; ++j) {
        int idx = i0 + threadIdx.x * 4 + j;
        v[j] = (idx < B) ? deg[idx] : 0;
        s += v[j];
    }
    ts[threadIdx.x] = s;
    __syncthreads();
    for (int o = 1; o < 256; o <<= 1) {
        int u = (threadIdx.x >= o) ? ts[threadIdx.x - o] : 0;
        __syncthreads();
        ts[threadIdx.x] += u;
        __syncthreads();
    }
    int run = chunkBase[blockIdx.x] + ts[threadIdx.x] - s;
    #pragma unroll
    for (int j = 0; j < 4; ++j) {
        int idx = i0 + threadIdx.x * 4 + j;
        if (idx <= B) off[idx] = run;
        run += v[j];
    }
}

__global__ __launch_bounds__(256)
void fill_csr(const int* __restrict__ src, const int* __restrict__ dst,
              int* __restrict__ cursor, int* __restrict__ esort, int nE)
{
    int e = blockIdx.x * 256 + threadIdx.x;
    if (e >= nE) return;
    int r = e / kER;
    int pos = atomicAdd(&cursor[r * kN + dst[e]], 1);
    esort[pos] = src[e];
}

// ---------------- aggregation ----------------

// one wave per (dst, j):  j<4 -> relation-j segsum;  j==4 -> copy own h row.
// agg[N][1280] bf16 = [4 relation segsums | own h row], nt-stored.
__global__ __launch_bounds__(256)
void aggregate_rel(const unsigned short* __restrict__ h, const int* __restrict__ off,
                   const int* __restrict__ esort, unsigned short* __restrict__ agg)
{
    const int lane = threadIdx.x & 63;
    const int gw = (int)((blockIdx.x * (size_t)blockDim.x + threadIdx.x) >> 6);
    const int d = gw / 5;
    const int j = gw - d * 5;
    if (d >= kN) return;
    const int c0 = lane * 4;

    if (j == 4) {
        us4 own = ld_u4(h + (size_t)d * kH + c0);
        nt_store_u4(agg + (size_t)d * 1280 + 1024 + c0, own);
        return;
    }

    float a0 = 0.f, a1 = 0.f, a2 = 0.f, a3 = 0.f;
    const int b  = off[j * kN + d];
    const int e2 = off[j * kN + d + 1];
    int t = b;
    for (; t + 4 <= e2; t += 4) {
        const int s0 = esort[t + 0];
        const int s1 = esort[t + 1];
        const int s2 = esort[t + 2];
        const int s3 = esort[t + 3];
        us4 v0 = ld_u4(h + (size_t)s0 * kH + c0);
        us4 v1 = ld_u4(h + (size_t)s1 * kH + c0);
        us4 v2 = ld_u4(h + (size_t)s2 * kH + c0);
        us4 v3 = ld_u4(h + (size_t)s3 * kH + c0);
        a0 += bf2f(v0.x) + bf2f(v1.x) + bf2f(v2.x) + bf2f(v3.x);
        a1 += bf2f(v0.y) + bf2f(v1.y) + bf2f(v2.y) + bf2f(v3.y);
        a2 += bf2f(v0.z) + bf2f(v1.z) + bf2f(v2.z) + bf2f(v3.z);
        a3 += bf2f(v0.w) + bf2f(v1.w) + bf2f(v2.w) + bf2f(v3.w);
    }
    for (; t < e2; ++t) {
        const int s = esort[t];
        us4 v = ld_u4(h + (size_t)s * kH + c0);
        a0 += bf2f(v.x); a1 += bf2f(v.y); a2 += bf2f(v.z); a3 += bf2f(v.w);
    }
    us4 o = { f2bf(a0), f2bf(a1), f2bf(a2), f2bf(a3) };
    nt_store_u4(agg + (size_t)d * 1280 + j * kH + c0, o);
}

// fallback: one relation, agg[N][256] bf16
__global__ __launch_bounds__(256)
void aggregate1_bf(const unsigned short* __restrict__ h, const int* __restrict__ off,
                   const int* __restrict__ esort, unsigned short* __restrict__ agg)
{
    const int lane = threadIdx.x & 63;
    const int d = (int)((blockIdx.x * (size_t)blockDim.x + threadIdx.x) >> 6);
    if (d >= kN) return;
    const int c0 = lane * 4;
    float a0 = 0.f, a1 = 0.f, a2 = 0.f, a3 = 0.f;
    const int b  = off[d];
    const int e2 = off[d + 1];
    for (int t = b; t < e2; ++t) {
        const int s = esort[t];
        us4 v = ld_u4(h + (size_t)s * kH + c0);
        a0 += bf2f(v.x); a1 += bf2f(v.y); a2 += bf2f(v.z); a3 += bf2f(v.w);
    }
    us4 o = { f2bf(a0), f2bf(a1), f2bf(a2), f2bf(a3) };
    *reinterpret_cast<us4*>(agg + (size_t)d * kH + c0) = o;
}

// h_bf16 = LN(xin_f32 [+ res_bf16]) * g + b   (one wave per row)
__global__ __launch_bounds__(256)
void ln_resid_bf(const float* __restrict__ xin, const unsigned short* __restrict__ res,
                 const float* __restrict__ g, const float* __restrict__ b,
                 unsigned short* __restrict__ out, int nRows)
{
    const int lane = threadIdx.x & 63;
    const int row  = (int)((blockIdx.x * (size_t)blockDim.x + threadIdx.x) >> 6);
    if (row >= nRows) return;
    f32x4 v = nt_load_f4(xin + (size_t)row * kH + lane * 4);
    if (res) {
        us4 rr = ld_u4(res + (size_t)row * kH + lane * 4);
        v.x += bf2f(rr.x); v.y += bf2f(rr.y); v.z += bf2f(rr.z); v.w += bf2f(rr.w);
    }
    float s = v.x + v.y + v.z + v.w;
    #pragma unroll
    for (int o = 32; o >= 1; o >>= 1) s += __shfl_xor(s, o);
    const float mu = s * (1.0f / kH);
    const float dx = v.x - mu, dy = v.y - mu, dz = v.z - mu, dw = v.w - mu;
    float q = dx * dx + dy * dy + dz * dz + dw * dw;
    #pragma unroll
    for (int o = 32; o >= 1; o >>= 1) q += __shfl_xor(q, o);
    const float rstd = rsqrtf(q * (1.0f / kH) + 1e-5f);
    const f32x4 gg = *reinterpret_cast<const f32x4*>(g + lane * 4);
    const f32x4 bb = *reinterpret_cast<const f32x4*>(b + lane * 4);
    us4 o4;
    o4.x = f2bf(dx * rstd * gg.x + bb.x);
    o4.y = f2bf(dy * rstd * gg.y + bb.y);
    o4.z = f2bf(dz * rstd * gg.z + bb.z);
    o4.w = f2bf(dw * rstd * gg.w + bb.w);
    *reinterpret_cast<us4*>(out + (size_t)row * kH + lane * 4) = o4;
}

// ------------------------------------------------------------------

extern "C" void kernel_launch(void* const* d_in, const int* in_sizes, int n_in,
                              void* d_out, int out_size, void* d_ws, size_t ws_size,
                              hipStream_t stream)
{
    const float* x_c  = (const float*)d_in[0];
    const float* x_t  = (const float*)d_in[1];
    const float* x_d  = (const float*)d_in[2];
    const int*   ei   = (const int*)d_in[3];
    const float* Wp_c = (const float*)d_in[4];
    const float* bp_c = (const float*)d_in[5];
    const float* Wp_t = (const float*)d_in[6];
    const float* bp_t = (const float*)d_in[7];
    const float* Wp_d = (const float*)d_in[8];
    const float* bp_d = (const float*)d_in[9];
    const float* rgcn_w    = (const float*)d_in[10];
    const float* rgcn_root = (const float*)d_in[11];
    const float* rgcn_b    = (const float*)d_in[12];
    const float* ln_g = (const float*)d_in[13];
    const float* ln_b = (const float*)d_in[14];
    const float* Wo   = (const float*)d_in[15];
    const float* bo   = (const float*)d_in[16];

    const int* src_base = ei;
    const int* dst_base = ei + (size_t)kE;

    const int nChunks = (kB + 1023) / 1024;
    const int pN  = padM(kN);    // 100096
    const int pNC = padM(kNC);   // 50048
    const int pNT = padM(kNT);   // 30080
    const int pND = padM(kND);   // 20096

    // ---- workspace carve
    char* p = (char*)d_ws;
    unsigned short* h_bf = (unsigned short*)p;  p += (size_t)pN * kH * 2;

    const size_t aggBytesFused = (size_t)pN * 1280 * 2;
    const size_t aggBytesSmall = (size_t)pN * kH * 2;
    const size_t xBytes = ((size_t)pNC * 256 + (size_t)pNT * 512 + (size_t)pND * 128) * 2;
    const size_t wBytes = ((size_t)256 * 256 + 256 * 512 + 256 * 128 +
                           2 * 256 * 1280 + 256 * 256) * 2;
    const size_t iBytes = ((size_t)kB + (kB + 1) + kE + 2048 + 64) * 4;

    const bool fused = ws_size >= (size_t)pN * kH * 2 + aggBytesFused + wBytes + iBytes + 256;

    unsigned short* agg = (unsigned short*)p;
    unsigned short* xbf_c;
    unsigned short* xbf_t;
    unsigned short* xbf_d;
    if (fused) {
        p += aggBytesFused;          // x aliases inside agg (used before layers)
        xbf_c = agg;
        xbf_t = xbf_c + (size_t)pNC * 256;
        xbf_d = xbf_t + (size_t)pNT * 512;
    } else {
        p += aggBytesSmall;
        xbf_c = (unsigned short*)p;  p += xBytes;
        xbf_t = xbf_c + (size_t)pNC * 256;
        xbf_d = xbf_t + (size_t)pNT * 512;
    }
    unsigned short* Wt_c = (unsigned short*)p;          // [256][256]
    unsigned short* Wt_t = Wt_c + 256 * 256;            // [256][512]
    unsigned short* Wt_d = Wt_t + 256 * 512;            // [256][128]
    unsigned short* Wst  = Wt_d + 256 * 128;            // [2][256][1280]
    unsigned short* Wt_o = Wst + 2 * 256 * 1280;        // [256][256]
    p = (char*)(Wt_o + 256 * 256);

    int* deg    = (int*)p;
    int* off    = deg + kB;
    int* esort  = off + (kB + 1);
    int* chunkS = esort + kE;
    int* chunkB = chunkS + 1024;

    float* outf = (float*)d_out;   // [N,256] f32: layer scratch + final y

    const dim3 blk(256);

    // ---- CSR build
    hipMemsetAsync(deg, 0, (size_t)kB * sizeof(int), stream);
    count_deg<<<dim3((kE + 255) / 256), blk, 0, stream>>>(dst_base, deg, kE);
    chunk_reduce<<<dim3(nChunks), blk, 0, stream>>>(deg, chunkS, kB);
    scan_chunks<<<dim3(1), dim3(64), 0, stream>>>(chunkS, chunkB, nChunks);
    scan_within<<<dim3(nChunks), blk, 0, stream>>>(deg, chunkB, off, kB);
    hipMemcpyAsync(deg, off, (size_t)kB * sizeof(int), hipMemcpyDeviceToDevice, stream);
    fill_csr<<<dim3((kE + 255) / 256), blk, 0, stream>>>(src_base, dst_base, deg, esort, kE);

    // ---- dtype prep
    conv_bf16<<<dim3((kNC * 256 / 4 + 255) / 256), blk, 0, stream>>>(x_c, xbf_c, kNC * 256);
    conv_bf16<<<dim3((kNT * 512 / 4 + 255) / 256), blk, 0, stream>>>(x_t, xbf_t, kNT * 512);
    conv_bf16<<<dim3((kND * 128 / 4 + 255) / 256), blk, 0, stream>>>(x_d, xbf_d, kND * 128);
    wT_bf16<<<dim3((256 * 256 + 255) / 256), blk, 0, stream>>>(Wp_c, Wt_c, 256);
    wT_bf16<<<dim3((256 * 512 + 255) / 256), blk, 0, stream>>>(Wp_t, Wt_t, 512);
    wT_bf16<<<dim3((256 * 128 + 255) / 256), blk, 0, stream>>>(Wp_d, Wt_d, 128);
    wT_bf16<<<dim3((256 * 256 + 255) / 256), blk, 0, stream>>>(Wo, Wt_o, 256);
    for (int l = 0; l < 2; ++l)
        wstack_bf16<<<dim3((256 * 1280 + 255) / 256), blk, 0, stream>>>(
            rgcn_w + (size_t)l * kR * kH * kH, rgcn_root + (size_t)l * kH * kH,
            Wst + (size_t)l * 256 * 1280);

    // ---- projections -> h_bf
    gemm_mfma<<<dim3(2, pNC / 128), blk, 0, stream>>>(
        xbf_c, 256, Wt_c, 256, bp_c, nullptr, h_bf, kNC, 256, 0);
    gemm_mfma<<<dim3(2, pNT / 128), blk, 0, stream>>>(
        xbf_t, 512, Wt_t, 512, bp_t, nullptr, h_bf + (size_t)kNC * kH, kNT, 512, 0);
    gemm_mfma<<<dim3(2, pND / 128), blk, 0, stream>>>(
        xbf_d, 128, Wt_d, 128, bp_d, nullptr, h_bf + (size_t)(kNC + kNT) * kH, kND, 128, 0);

    const dim3 gemmN(2, pN / 128);
    const dim3 waveGrid((int)(((size_t)kN * 64 + 255) / 256));
    const dim3 aggGrid5((int)(((size_t)kN * 5 * 64 + 255) / 256));

    for (int l = 0; l < 2; ++l) {
        if (fused) {
            aggregate_rel<<<aggGrid5, blk, 0, stream>>>(h_bf, off, esort, agg);
            gemm_mfma<<<gemmN, blk, 0, stream>>>(
                agg, 1280, Wst + (size_t)l * 256 * 1280, 1280,
                rgcn_b + (size_t)l * kH, outf, nullptr, kN, 1280, 0);
        } else {
            gemm_mfma<<<gemmN, blk, 0, stream>>>(
                h_bf, 256, Wst + (size_t)l * 256 * 1280 + 1024, 1280,
                rgcn_b + (size_t)l * kH, outf, nullptr, kN, 256, 0);
            for (int r = 0; r < kR; ++r) {
                aggregate1_bf<<<waveGrid, blk, 0, stream>>>(h_bf, off + (size_t)r * kN, esort, agg);
                gemm_mfma<<<gemmN, blk, 0, stream>>>(
                    agg, 256, Wst + (size_t)l * 256 * 1280 + (size_t)r * 256, 1280,
                    nullptr, outf, nullptr, kN, 256, 1);
            }
        }
        ln_resid_bf<<<waveGrid, blk, 0, stream>>>(
            outf, (l > 0) ? h_bf : nullptr, ln_g + (size_t)l * kH, ln_b + (size_t)l * kH,
            h_bf, kN);
    }

    // ---- final: y = h @ Wo + bo -> d_out (f32)
    gemm_mfma<<<gemmN, blk, 0, stream>>>(
        h_bf, 256, Wt_o, 256, bo, outf, nullptr, kN, 256, 0);
}

// Round 6
// 1057.780 us; speedup vs baseline: 14.2633x; 1.0917x over previous
//
#include <hip/hip_runtime.h>
#include <hip/hip_bf16.h>

namespace {
constexpr int kNC = 50000;
constexpr int kNT = 30000;
constexpr int kND = 20000;
constexpr int kN  = 100000;   // total nodes
constexpr int kR  = 4;        // relations
constexpr int kER = 400000;   // edges per relation
constexpr int kE  = kR * kER; // 1.6M edges
constexpr int kH  = 256;      // hidden dim
constexpr int kB  = kR * kN;  // CSR buckets (relation-major)

constexpr int padM(int m) { return (m + 127) / 128 * 128; }
}

typedef __attribute__((ext_vector_type(8))) short short8;
typedef __attribute__((ext_vector_type(4))) float f32x4;
typedef __attribute__((ext_vector_type(4))) unsigned short us4;

__device__ __forceinline__ unsigned short f2bf(float x) {
    unsigned u = __builtin_bit_cast(unsigned, x);
    u += 0x7FFF + ((u >> 16) & 1);      // RNE
    return (unsigned short)(u >> 16);
}
__device__ __forceinline__ float bf2f(unsigned short u) {
    unsigned v = ((unsigned)u) << 16;
    return __builtin_bit_cast(float, v);
}

__device__ __forceinline__ void gld16(const void* src, void* lds) {
    __builtin_amdgcn_global_load_lds(
        (const __attribute__((address_space(1))) void*)src,
        (__attribute__((address_space(3))) void*)lds, 16, 0, 0);
}

__device__ __forceinline__ us4 ld_u4(const unsigned short* p) {
    return *reinterpret_cast<const us4*>(p);
}
__device__ __forceinline__ void nt_store_f(float* p, float v) {
    __builtin_nontemporal_store(v, p);
}

// ------------------------------------------------------------------
// bf16 MFMA GEMM (used for projections + final):
// C[M,256] = A[M,K](bf16) @ Bt[256,K]^T(bf16) + bias
// ------------------------------------------------------------------
__global__ __launch_bounds__(256)
void gemm_mfma(const unsigned short* __restrict__ A, int lda,
               const unsigned short* __restrict__ Bt, int ldb,
               const float* __restrict__ bias,
               float* __restrict__ Cf, unsigned short* __restrict__ Cb,
               int M, int K, int accumulate)
{
    __shared__ __attribute__((aligned(16))) unsigned short As[128 * 32];
    __shared__ __attribute__((aligned(16))) unsigned short Bs[128 * 32];
    const int tid  = threadIdx.x;
    const int lane = tid & 63;
    const int wid  = tid >> 6;
    const int wm   = wid >> 1;
    const int wn   = wid & 1;
    const int row0 = blockIdx.y * 128;
    const int col0 = blockIdx.x * 128;

    const int cr = lane >> 2;
    const int cs = lane & 3;

    const f32x4 z4 = {0.f, 0.f, 0.f, 0.f};
    f32x4 acc[4][4];
    #pragma unroll
    for (int m = 0; m < 4; ++m)
        #pragma unroll
        for (int n = 0; n < 4; ++n) acc[m][n] = z4;

    const int fr = lane & 15;
    const int kb = lane >> 4;

    for (int k0 = 0; k0 < K; k0 += 32) {
        #pragma unroll
        for (int j = 0; j < 2; ++j) {
            const int chunk = wid * 2 + j;
            const int r  = chunk * 16 + cr;
            const int sg = cs ^ ((r >> 1) & 3);
            gld16(A  + (size_t)(row0 + r) * lda + k0 + sg * 8, As + chunk * 512);
            gld16(Bt + (size_t)(col0 + r) * ldb + k0 + sg * 8, Bs + chunk * 512);
        }
        __syncthreads();
        short8 a[4], b[4];
        #pragma unroll
        for (int m = 0; m < 4; ++m) {
            const int am = wm * 64 + m * 16 + fr;
            const int s  = kb ^ ((am >> 1) & 3);
            a[m] = *(const short8*)(As + am * 32 + s * 8);
        }
        #pragma unroll
        for (int n = 0; n < 4; ++n) {
            const int bn = wn * 64 + n * 16 + fr;
            const int s  = kb ^ ((bn >> 1) & 3);
            b[n] = *(const short8*)(Bs + bn * 32 + s * 8);
        }
        #pragma unroll
        for (int m = 0; m < 4; ++m)
            #pragma unroll
            for (int n = 0; n < 4; ++n)
                acc[m][n] = __builtin_amdgcn_mfma_f32_16x16x32_bf16(
                    a[m], b[n], acc[m][n], 0, 0, 0);
        __syncthreads();
    }

    const int fq = lane >> 4;
    #pragma unroll
    for (int m = 0; m < 4; ++m) {
        #pragma unroll
        for (int n = 0; n < 4; ++n) {
            const int col  = col0 + wn * 64 + n * 16 + fr;
            const int rowb = row0 + wm * 64 + m * 16 + fq * 4;
            const float bv = bias ? bias[col] : 0.0f;
            #pragma unroll
            for (int i = 0; i < 4; ++i) {
                const int row = rowb + i;
                if (row >= M) continue;
                const float v = acc[m][n][i] + bv;
                const size_t idx = (size_t)row * kH + col;
                if (Cb) Cb[idx] = f2bf(v);
                else if (accumulate) Cf[idx] += v;
                else nt_store_f(&Cf[idx], v);
            }
        }
    }
}

// ------------------------------------------------------------------
// Fused RGCN layer: per block of 64 dst rows x 256 cols:
//   acc = sum_r segsum_r(h) @ W_r + h @ root           (MFMA, K=256 x5)
//   out = LN(acc + bias [+ h]) * g + b  -> h_nxt (bf16)
// A-tile gathered/copied into swizzled LDS; B streamed via gld16 with
// pre-swizzled global source. h_cur (51 MB) stays L3-resident.
// ------------------------------------------------------------------
__device__ __forceinline__ void stageB_slice(const unsigned short* __restrict__ Wt,
                                             char* bsBase, int kidx, int wid, int lane)
{
    #pragma unroll
    for (int issue = 0; issue < 2; ++issue) {
        const int base = issue * 8192 + wid * 1024;
        const int o = base + lane * 16;
        const int col = o >> 6;
        const int slot = (o >> 4) & 3;
        const int slot_g = slot ^ (col & 3);
        gld16(Wt + (size_t)col * 1280 + kidx + slot_g * 8, bsBase + base);
    }
}

__global__ __launch_bounds__(512, 4)
void rgcn_fused(const unsigned short* __restrict__ h_cur,
                const int* __restrict__ off, const int* __restrict__ esort,
                const unsigned short* __restrict__ Wt,   // [256 cols][1280 k]
                const float* __restrict__ bias, const float* __restrict__ g,
                const float* __restrict__ b,
                unsigned short* __restrict__ h_nxt, int useResid)
{
    __shared__ __attribute__((aligned(16))) unsigned short A_seg[64 * 256]; // 32 KB
    __shared__ __attribute__((aligned(16))) unsigned short Bs[2][256 * 32]; // 2x16 KB
    __shared__ float red[2][4][64];                                          // 2 KB
    __shared__ float gcol[256], bcol[256], biascol[256];                     // 3 KB

    const int tid  = threadIdx.x;
    const int lane = tid & 63;
    const int wid  = tid >> 6;     // 0..7
    const int wm   = wid >> 2;     // 0..1 (row half)
    const int wn   = wid & 3;      // 0..3 (col quarter)
    const int row0 = blockIdx.x * 64;
    const int fr   = lane & 15;
    const int kb   = lane >> 4;

    if (tid < 256) { gcol[tid] = g[tid]; bcol[tid] = b[tid]; biascol[tid] = bias[tid]; }

    const f32x4 z4 = {0.f, 0.f, 0.f, 0.f};
    f32x4 acc[2][4];
    #pragma unroll
    for (int m = 0; m < 2; ++m)
        #pragma unroll
        for (int n = 0; n < 4; ++n) acc[m][n] = z4;

    char* const aBase = reinterpret_cast<char*>(A_seg);

    for (int p = 0; p < 5; ++p) {
        __syncthreads();    // previous phase's MFMA reads of A_seg/Bs done
        if (p < 4) {
            // gather segsum for relation p: wave handles 8 rows
            for (int j = 0; j < 8; ++j) {
                const int wrow = wid * 8 + j;
                const int d = row0 + wrow;
                float a0 = 0.f, a1 = 0.f, a2 = 0.f, a3 = 0.f;
                if (d < kN) {
                    const int t0 = off[p * kN + d];
                    const int t1 = off[p * kN + d + 1];
                    int t = t0;
                    for (; t + 4 <= t1; t += 4) {
                        const int s0 = esort[t + 0];
                        const int s1 = esort[t + 1];
                        const int s2 = esort[t + 2];
                        const int s3 = esort[t + 3];
                        us4 v0 = ld_u4(h_cur + (size_t)s0 * kH + lane * 4);
                        us4 v1 = ld_u4(h_cur + (size_t)s1 * kH + lane * 4);
                        us4 v2 = ld_u4(h_cur + (size_t)s2 * kH + lane * 4);
                        us4 v3 = ld_u4(h_cur + (size_t)s3 * kH + lane * 4);
                        a0 += bf2f(v0.x) + bf2f(v1.x) + bf2f(v2.x) + bf2f(v3.x);
                        a1 += bf2f(v0.y) + bf2f(v1.y) + bf2f(v2.y) + bf2f(v3.y);
                        a2 += bf2f(v0.z) + bf2f(v1.z) + bf2f(v2.z) + bf2f(v3.z);
                        a3 += bf2f(v0.w) + bf2f(v1.w) + bf2f(v2.w) + bf2f(v3.w);
                    }
                    for (; t < t1; ++t) {
                        const int s = esort[t];
                        us4 v = ld_u4(h_cur + (size_t)s * kH + lane * 4);
                        a0 += bf2f(v.x); a1 += bf2f(v.y); a2 += bf2f(v.z); a3 += bf2f(v.w);
                    }
                }
                us4 o = { f2bf(a0), f2bf(a1), f2bf(a2), f2bf(a3) };
                const int byte = (wrow * 512 + lane * 8) ^ ((wrow & 7) << 4);
                *reinterpret_cast<us4*>(aBase + byte) = o;
            }
        } else {
            // root: copy own h-tile (coalesced; swizzle via source address)
            #pragma unroll
            for (int i = 0; i < 4; ++i) {
                const int base = i * 8192 + wid * 1024;
                const int o = base + lane * 16;
                const int row = o >> 9;
                const int offr = (o & 511) ^ ((row & 7) << 4);
                gld16(h_cur + (size_t)(row0 + row) * kH + (offr >> 1), aBase + base);
            }
        }
        const int kbase = (p < 4) ? p * 256 : 1024;
        stageB_slice(Wt, reinterpret_cast<char*>(Bs[0]), kbase, wid, lane);

        for (int ks = 0; ks < 8; ++ks) {
            __syncthreads();   // drains vmcnt+lgkm: A_seg & Bs[ks&1] ready
            if (ks < 7)
                stageB_slice(Wt, reinterpret_cast<char*>(Bs[(ks + 1) & 1]),
                             kbase + (ks + 1) * 32, wid, lane);
            const int kByte = ks * 64 + kb * 16;
            short8 a[2], bf[4];
            #pragma unroll
            for (int m = 0; m < 2; ++m) {
                const int am = wm * 32 + m * 16 + fr;
                const int byte = (am * 512 + kByte) ^ ((am & 7) << 4);
                a[m] = *reinterpret_cast<const short8*>(aBase + byte);
            }
            char* const bBase = reinterpret_cast<char*>(Bs[ks & 1]);
            #pragma unroll
            for (int n = 0; n < 4; ++n) {
                const int cn = wn * 64 + n * 16 + fr;
                const int byte = cn * 64 + ((kb ^ (cn & 3)) << 4);
                bf[n] = *reinterpret_cast<const short8*>(bBase + byte);
            }
            #pragma unroll
            for (int m = 0; m < 2; ++m)
                #pragma unroll
                for (int n = 0; n < 4; ++n)
                    acc[m][n] = __builtin_amdgcn_mfma_f32_16x16x32_bf16(
                        a[m], bf[n], acc[m][n], 0, 0, 0);
        }
    }

    // ---- epilogue: bias + residual + LayerNorm, write h_nxt (bf16)
    const int fq = lane >> 4;
    #pragma unroll
    for (int m = 0; m < 2; ++m) {
        #pragma unroll
        for (int i = 0; i < 4; ++i) {
            const int rowloc = wm * 32 + m * 16 + fq * 4 + i;
            const int row = row0 + rowloc;
            float s = 0.f, q = 0.f;
            #pragma unroll
            for (int n = 0; n < 4; ++n) {
                const int col = wn * 64 + n * 16 + fr;
                float v = acc[m][n][i] + biascol[col];
                if (useResid) v += bf2f(h_cur[(size_t)row * kH + col]);
                acc[m][n][i] = v;
                s += v;
                q += v * v;
            }
            #pragma unroll
            for (int w = 1; w <= 8; w <<= 1) {
                s += __shfl_xor(s, w);
                q += __shfl_xor(q, w);
            }
            if (fr == 0) { red[0][wn][rowloc] = s; red[1][wn][rowloc] = q; }
        }
    }
    __syncthreads();
    #pragma unroll
    for (int m = 0; m < 2; ++m) {
        #pragma unroll
        for (int i = 0; i < 4; ++i) {
            const int rowloc = wm * 32 + m * 16 + fq * 4 + i;
            const int row = row0 + rowloc;
            const float s  = red[0][0][rowloc] + red[0][1][rowloc]
                           + red[0][2][rowloc] + red[0][3][rowloc];
            const float qq = red[1][0][rowloc] + red[1][1][rowloc]
                           + red[1][2][rowloc] + red[1][3][rowloc];
            const float mu = s * (1.0f / kH);
            const float var = qq * (1.0f / kH) - mu * mu;
            const float rstd = rsqrtf(var + 1e-5f);
            if (row < kN) {
                #pragma unroll
                for (int n = 0; n < 4; ++n) {
                    const int col = wn * 64 + n * 16 + fr;
                    const float o = (acc[m][n][i] - mu) * rstd * gcol[col] + bcol[col];
                    h_nxt[(size_t)row * kH + col] = f2bf(o);
                }
            }
        }
    }
}

// ---------------- dtype prep ----------------

__global__ __launch_bounds__(256)
void conv_bf16(const float* __restrict__ in, unsigned short* __restrict__ out, int n)
{
    int i = (blockIdx.x * 256 + threadIdx.x) * 4;
    if (i >= n) return;
    f32x4 v = *reinterpret_cast<const f32x4*>(in + i);
    us4 o = { f2bf(v.x), f2bf(v.y), f2bf(v.z), f2bf(v.w) };
    *reinterpret_cast<us4*>(out + i) = o;
}

// W [K][256] f32 -> Wt [256][K] bf16
__global__ __launch_bounds__(256)
void wT_bf16(const float* __restrict__ W, unsigned short* __restrict__ Wt, int K)
{
    int t = blockIdx.x * 256 + threadIdx.x;
    if (t >= 256 * K) return;
    int c = t / K, k = t % K;
    Wt[t] = f2bf(W[(size_t)k * 256 + c]);
}

// [w(4x256x256); root(256x256)] -> Wt [256][1280] bf16
__global__ __launch_bounds__(256)
void wstack_bf16(const float* __restrict__ w, const float* __restrict__ root,
                 unsigned short* __restrict__ Wt)
{
    int t = blockIdx.x * 256 + threadIdx.x;
    if (t >= 256 * 1280) return;
    int c = t / 1280, k = t % 1280;
    float v = (k < 1024) ? w[(size_t)((k >> 8) * 256 + (k & 255)) * 256 + c]
                         : root[(size_t)(k - 1024) * 256 + c];
    Wt[t] = f2bf(v);
}

// ---------------- CSR build ----------------

__global__ __launch_bounds__(256)
void count_deg(const int* __restrict__ dst, int* __restrict__ deg, int nE)
{
    int e = blockIdx.x * 256 + threadIdx.x;
    if (e >= nE) return;
    int r = e / kER;
    atomicAdd(&deg[r * kN + dst[e]], 1);
}

__global__ __launch_bounds__(256)
void chunk_reduce(const int* __restrict__ deg, int* __restrict__ chunkSum, int B)
{
    __shared__ int sm[256];
    int s = 0;
    #pragma unroll
    for (int j = 0; j < 4; ++j) {
        int idx = blockIdx.x * 1024 + j * 256 + threadIdx.x;
        if (idx < B) s += deg[idx];
    }
    sm[threadIdx.x] = s;
    __syncthreads();
    for (int o = 128; o >= 1; o >>= 1) {
        if (threadIdx.x < o) sm[threadIdx.x] += sm[threadIdx.x + o];
        __syncthreads();
    }
    if (threadIdx.x == 0) chunkSum[blockIdx.x] = sm[0];
}

__global__ __launch_bounds__(64)
void scan_chunks(const int* __restrict__ chunkSum, int* __restrict__ chunkBase, int n)
{
    int lane = threadIdx.x;
    int base = 0;
    for (int i0 = 0; i0 < n; i0 += 64) {
        int i = i0 + lane;
        int orig = (i < n) ? chunkSum[i] : 0;
        int v = orig;
        #pragma unroll
        for (int o = 1; o < 64; o <<= 1) {
            int t = __shfl_up(v, o);
            if (lane >= o) v += t;
        }
        if (i < n) chunkBase[i] = base + v - orig;
        base += __shfl(v, 63);
    }
}

__global__ __launch_bounds__(256)
void scan_within(const int* __restrict__ deg, const int* __restrict__ chunkBase,
                 int* __restrict__ off, int B)
{
    __shared__ int ts[256];
    const int i0 = blockIdx.x * 1024;
    int v[4];
    int s = 0;
    #pragma unroll
    for (int j = 0; j < 4; ++j) {
        int idx = i0 + threadIdx.x * 4 + j;
        v[j] = (idx < B) ? deg[idx] : 0;
        s += v[j];
    }
    ts[threadIdx.x] = s;
    __syncthreads();
    for (int o = 1; o < 256; o <<= 1) {
        int u = (threadIdx.x >= o) ? ts[threadIdx.x - o] : 0;
        __syncthreads();
        ts[threadIdx.x] += u;
        __syncthreads();
    }
    int run = chunkBase[blockIdx.x] + ts[threadIdx.x] - s;
    #pragma unroll
    for (int j = 0; j < 4; ++j) {
        int idx = i0 + threadIdx.x * 4 + j;
        if (idx <= B) off[idx] = run;
        run += v[j];
    }
}

__global__ __launch_bounds__(256)
void fill_csr(const int* __restrict__ src, const int* __restrict__ dst,
              int* __restrict__ cursor, int* __restrict__ esort, int nE)
{
    int e = blockIdx.x * 256 + threadIdx.x;
    if (e >= nE) return;
    int r = e / kER;
    int pos = atomicAdd(&cursor[r * kN + dst[e]], 1);
    esort[pos] = src[e];
}

// ------------------------------------------------------------------

extern "C" void kernel_launch(void* const* d_in, const int* in_sizes, int n_in,
                              void* d_out, int out_size, void* d_ws, size_t ws_size,
                              hipStream_t stream)
{
    const float* x_c  = (const float*)d_in[0];
    const float* x_t  = (const float*)d_in[1];
    const float* x_d  = (const float*)d_in[2];
    const int*   ei   = (const int*)d_in[3];
    const float* Wp_c = (const float*)d_in[4];
    const float* bp_c = (const float*)d_in[5];
    const float* Wp_t = (const float*)d_in[6];
    const float* bp_t = (const float*)d_in[7];
    const float* Wp_d = (const float*)d_in[8];
    const float* bp_d = (const float*)d_in[9];
    const float* rgcn_w    = (const float*)d_in[10];
    const float* rgcn_root = (const float*)d_in[11];
    const float* rgcn_b    = (const float*)d_in[12];
    const float* ln_g = (const float*)d_in[13];
    const float* ln_b = (const float*)d_in[14];
    const float* Wo   = (const float*)d_in[15];
    const float* bo   = (const float*)d_in[16];

    const int* src_base = ei;
    const int* dst_base = ei + (size_t)kE;

    const int nChunks = (kB + 1023) / 1024;
    const int pN  = padM(kN);    // 100096
    const int pNC = padM(kNC);
    const int pNT = padM(kNT);
    const int pND = padM(kND);

    // ---- workspace carve
    char* p = (char*)d_ws;
    unsigned short* hA = (unsigned short*)p;  p += (size_t)pN * kH * 2;
    unsigned short* hB = (unsigned short*)p;  p += (size_t)pN * kH * 2;
    unsigned short* xbf_c = (unsigned short*)p;  p += (size_t)pNC * 256 * 2;
    unsigned short* xbf_t = (unsigned short*)p;  p += (size_t)pNT * 512 * 2;
    unsigned short* xbf_d = (unsigned short*)p;  p += (size_t)pND * 128 * 2;
    unsigned short* Wt_c = (unsigned short*)p;          // [256][256]
    unsigned short* Wt_t = Wt_c + 256 * 256;            // [256][512]
    unsigned short* Wt_d = Wt_t + 256 * 512;            // [256][128]
    unsigned short* Wst  = Wt_d + 256 * 128;            // [2][256][1280]
    unsigned short* Wt_o = Wst + 2 * 256 * 1280;        // [256][256]
    p = (char*)(Wt_o + 256 * 256);

    int* deg    = (int*)p;
    int* off    = deg + kB;
    int* esort  = off + (kB + 1);
    int* chunkS = esort + kE;
    int* chunkB = chunkS + 1024;

    float* outf = (float*)d_out;   // final y (f32)

    const dim3 blk(256);

    // ---- CSR build
    hipMemsetAsync(deg, 0, (size_t)kB * sizeof(int), stream);
    count_deg<<<dim3((kE + 255) / 256), blk, 0, stream>>>(dst_base, deg, kE);
    chunk_reduce<<<dim3(nChunks), blk, 0, stream>>>(deg, chunkS, kB);
    scan_chunks<<<dim3(1), dim3(64), 0, stream>>>(chunkS, chunkB, nChunks);
    scan_within<<<dim3(nChunks), blk, 0, stream>>>(deg, chunkB, off, kB);
    hipMemcpyAsync(deg, off, (size_t)kB * sizeof(int), hipMemcpyDeviceToDevice, stream);
    fill_csr<<<dim3((kE + 255) / 256), blk, 0, stream>>>(src_base, dst_base, deg, esort, kE);

    // ---- dtype prep
    conv_bf16<<<dim3((kNC * 256 / 4 + 255) / 256), blk, 0, stream>>>(x_c, xbf_c, kNC * 256);
    conv_bf16<<<dim3((kNT * 512 / 4 + 255) / 256), blk, 0, stream>>>(x_t, xbf_t, kNT * 512);
    conv_bf16<<<dim3((kND * 128 / 4 + 255) / 256), blk, 0, stream>>>(x_d, xbf_d, kND * 128);
    wT_bf16<<<dim3((256 * 256 + 255) / 256), blk, 0, stream>>>(Wp_c, Wt_c, 256);
    wT_bf16<<<dim3((256 * 512 + 255) / 256), blk, 0, stream>>>(Wp_t, Wt_t, 512);
    wT_bf16<<<dim3((256 * 128 + 255) / 256), blk, 0, stream>>>(Wp_d, Wt_d, 128);
    wT_bf16<<<dim3((256 * 256 + 255) / 256), blk, 0, stream>>>(Wo, Wt_o, 256);
    for (int l = 0; l < 2; ++l)
        wstack_bf16<<<dim3((256 * 1280 + 255) / 256), blk, 0, stream>>>(
            rgcn_w + (size_t)l * kR * kH * kH, rgcn_root + (size_t)l * kH * kH,
            Wst + (size_t)l * 256 * 1280);

    // ---- projections -> hA
    gemm_mfma<<<dim3(2, pNC / 128), blk, 0, stream>>>(
        xbf_c, 256, Wt_c, 256, bp_c, nullptr, hA, kNC, 256, 0);
    gemm_mfma<<<dim3(2, pNT / 128), blk, 0, stream>>>(
        xbf_t, 512, Wt_t, 512, bp_t, nullptr, hA + (size_t)kNC * kH, kNT, 512, 0);
    gemm_mfma<<<dim3(2, pND / 128), blk, 0, stream>>>(
        xbf_d, 128, Wt_d, 128, bp_d, nullptr, hA + (size_t)(kNC + kNT) * kH, kND, 128, 0);

    // ---- fused RGCN layers (h double-buffered: hA -> hB -> hA)
    const dim3 fusedGrid((kN + 63) / 64);
    const dim3 fusedBlk(512);
    rgcn_fused<<<fusedGrid, fusedBlk, 0, stream>>>(
        hA, off, esort, Wst, rgcn_b, ln_g, ln_b, hB, 0);
    rgcn_fused<<<fusedGrid, fusedBlk, 0, stream>>>(
        hB, off, esort, Wst + (size_t)256 * 1280,
        rgcn_b + kH, ln_g + kH, ln_b + kH, hA, 1);

    // ---- final: y = h @ Wo + bo -> d_out (f32)
    gemm_mfma<<<dim3(2, pN / 128), blk, 0, stream>>>(
        hA, 256, Wt_o, 256, bo, outf, nullptr, kN, 256, 0);
}